// Round 9
// baseline (184.580 us; speedup 1.0000x reference)
//
#include <hip/hip_runtime.h>
#include <hip/hip_bf16.h>
#include <math.h>

#define EPSF 1e-6f

// clang native vector type — required by __builtin_nontemporal_load
typedef float float4n __attribute__((ext_vector_type(4)));

__device__ inline float readlane_f(float v, int l) {
    return __int_as_float(__builtin_amdgcn_readlane(__float_as_int(v), l));
}

// ---------------------------------------------------------------------------
// Kernel A (unchanged from R7 measured config): bucket means for q and k.
// One WAVE per (tensor, bh, bucket): 4096 waves -> 1024 blocks x 256.
// 32 nt float4 loads/lane in 2 batches of 16, shfl_xor(16,32) reduce.
// ---------------------------------------------------------------------------
__global__ __launch_bounds__(256) void bucket_mean_kernel(
    const float* __restrict__ q,
    const float* __restrict__ k,
    float* __restrict__ sqk)  // [2][32][64][64]
{
    int g      = blockIdx.x * 4 + (threadIdx.x >> 6);
    int t      = g >> 11;        // 0 = q, 1 = k
    int bh     = (g >> 6) & 31;
    int bucket = g & 63;

    const float* src = t ? k : q;
    const float4n* base = reinterpret_cast<const float4n*>(
        src + ((size_t)bh * 8192 + (size_t)bucket * 128) * 64);

    int lane = threadIdx.x & 63;
    int rr   = lane >> 4;        // 0..3
    int c    = lane & 15;        // 0..15

    float4n acc = (float4n)(0.f);
    #pragma unroll
    for (int b = 0; b < 2; ++b) {
        float4n v[16];
        #pragma unroll
        for (int u = 0; u < 16; ++u)
            v[u] = __builtin_nontemporal_load(&base[(rr + (b * 16 + u) * 4) * 16 + c]);
        #pragma unroll
        for (int u = 0; u < 16; ++u)
            acc += v[u];
    }

    acc.x += __shfl_xor(acc.x, 16, 64);
    acc.y += __shfl_xor(acc.y, 16, 64);
    acc.z += __shfl_xor(acc.z, 16, 64);
    acc.w += __shfl_xor(acc.w, 16, 64);
    acc.x += __shfl_xor(acc.x, 32, 64);
    acc.y += __shfl_xor(acc.y, 32, 64);
    acc.z += __shfl_xor(acc.z, 32, 64);
    acc.w += __shfl_xor(acc.w, 32, 64);

    if (lane < 16) {
        acc *= (1.0f / 128.0f);
        float4n* dst = reinterpret_cast<float4n*>(
            sqk + (size_t)t * 32 * 64 * 64 + ((size_t)bh * 64 + bucket) * 64);
        dst[c] = acc;
    }
}

// ---------------------------------------------------------------------------
// Kernel B v2: dot phase parallel (16 waves), then BARRIER-FREE sinkhorn on
// wave 0 in probability space: the whole 64x64 matrix lives in 64 regs/lane
// (lane = column j, reg = row i). log-space (r -= lse) == prob-space
// (s /= sum), and out = exp(r) == s, so iterations need no exp/log at all.
// Row-norm (axis=2): 6-step shfl_xor butterfly per reg.
// Col-norm (axis=1): per-lane register sum.
// ---------------------------------------------------------------------------
__global__ __launch_bounds__(1024) void sinkhorn_kernel(
    const float* __restrict__ sqk,      // [2][32][64][64]
    const float* __restrict__ u_gumbel, // [32][64][64]
    float* __restrict__ out)            // [32][64][64]
{
    int bh  = blockIdx.x;
    int tid = threadIdx.x;

    __shared__ float sk_s[64][65];
    __shared__ float s_s[64][65];

    const float* sqp = sqk + (size_t)bh * 4096;
    const float* skp = sqk + (size_t)32 * 4096 + (size_t)bh * 4096;

    // stage sk into LDS (4096 elems / 1024 threads)
    #pragma unroll
    for (int t = 0; t < 4; ++t) {
        int idx = tid + 1024 * t;
        sk_s[idx >> 6][idx & 63] = skp[idx];
    }

    int lane = tid & 63;
    int i0   = tid >> 6;              // wave id 0..15

    // sq rows for this wave, in registers: lane e holds sq[i][e]
    float sqr0 = sqp[(i0     ) * 64 + lane];
    float sqr1 = sqp[(i0 + 16) * 64 + lane];
    float sqr2 = sqp[(i0 + 32) * 64 + lane];
    float sqr3 = sqp[(i0 + 48) * 64 + lane];
    __syncthreads();

    {   // R = sq·sk^T/8; s = exp((log(relu(R)+eps)+gumbel)/T)
        int j = lane;
        float acc0 = 0.f, acc1 = 0.f, acc2 = 0.f, acc3 = 0.f;
        #pragma unroll
        for (int e = 0; e < 64; ++e) {
            float s = sk_s[j][e];
            acc0 = fmaf(readlane_f(sqr0, e), s, acc0);
            acc1 = fmaf(readlane_f(sqr1, e), s, acc1);
            acc2 = fmaf(readlane_f(sqr2, e), s, acc2);
            acc3 = fmaf(readlane_f(sqr3, e), s, acc3);
        }
        const float scale = 0.125f;
        const float invT  = 1.0f / 0.7f;
        float accs[4] = {acc0, acc1, acc2, acc3};
        #pragma unroll
        for (int t = 0; t < 4; ++t) {
            int i   = i0 + 16 * t;
            float rl = fmaxf(accs[t] * scale, 0.f);
            float u  = u_gumbel[(size_t)bh * 4096 + i * 64 + j];
            float gm = -__logf(-__logf(u + EPSF) + EPSF);
            s_s[i][j] = __expf((__logf(rl + EPSF) + gm) * invT);
        }
    }
    __syncthreads();

    if (tid < 64) {                   // wave 0: barrier-free sinkhorn
        float s[64];
        #pragma unroll
        for (int i = 0; i < 64; ++i) s[i] = s_s[i][tid];

        #pragma unroll 1
        for (int it = 0; it < 8; ++it) {
            // axis=2 (over j = lanes): butterfly row-sum, then normalize
            #pragma unroll
            for (int i = 0; i < 64; ++i) {
                float t = s[i];
                t += __shfl_xor(t, 1, 64);
                t += __shfl_xor(t, 2, 64);
                t += __shfl_xor(t, 4, 64);
                t += __shfl_xor(t, 8, 64);
                t += __shfl_xor(t, 16, 64);
                t += __shfl_xor(t, 32, 64);
                s[i] *= __builtin_amdgcn_rcpf(t);
            }
            // axis=1 (over i = regs): per-lane sum with 4-way ILP
            float t0 = 0.f, t1 = 0.f, t2 = 0.f, t3 = 0.f;
            #pragma unroll
            for (int i = 0; i < 64; i += 4) {
                t0 += s[i]; t1 += s[i + 1]; t2 += s[i + 2]; t3 += s[i + 3];
            }
            float rc = __builtin_amdgcn_rcpf((t0 + t1) + (t2 + t3));
            #pragma unroll
            for (int i = 0; i < 64; ++i) s[i] *= rc;
        }

        #pragma unroll
        for (int i = 0; i < 64; ++i) s_s[i][tid] = s[i];
    }
    __syncthreads();

    // out = s (already probability space)
    #pragma unroll
    for (int t = 0; t < 4; ++t) {
        int idx = tid + 1024 * t;
        out[(size_t)bh * 4096 + idx] = s_s[idx >> 6][idx & 63];
    }
}

extern "C" void kernel_launch(void* const* d_in, const int* in_sizes, int n_in,
                              void* d_out, int out_size, void* d_ws, size_t ws_size,
                              hipStream_t stream) {
    const float* q = (const float*)d_in[0];        // [32,8192,64]
    const float* k = (const float*)d_in[1];        // [32,8192,64]
    const float* u = (const float*)d_in[2];        // [32,64,64]
    float* out = (float*)d_out;                    // [32,64,64]
    float* sqk = (float*)d_ws;                     // [2][32][64][64] = 1 MiB

    bucket_mean_kernel<<<1024, 256, 0, stream>>>(q, k, sqk);
    sinkhorn_kernel<<<32, 1024, 0, stream>>>(sqk, u, out);
}